// Round 10
// baseline (98.179 us; speedup 1.0000x reference)
//
#include <hip/hip_runtime.h>

// B=2, N_mm=64, N_a=N_v=256, DIM=512, H=8, hd=64, scale=1/8.
// Factorized: softmax over (i,j) grid with logits Av_i+Aa_j, values vv_i+va_j
// = SUM of two independently-normalized 256-key attentions:
//   out = (Σ_i softmax_i(Av) vv_i) + (Σ_j softmax_j(Aa) va_j).
//
// R9 ablation: attn steady-state = 4.7us but FIRST read of K1's slabs pays
// ~20us cross-XCD dirty-L2 penalty. Fix: fuse projections INTO the consumer
// block (per b,h,side), operands loaded straight from the f32 inputs, K/V/q
// accumulators transposed in-block into LDS. No slab handoff. 2 kernels:
//   K1: fused proj+attention, 32 blocks x 512 thr -> hv/ha (f32, 512 KB)
//   K2: out = (hv+ha) @ Wproj.T + bproj, 16 blocks x 256 thr

typedef _Float16 f16x8 __attribute__((ext_vector_type(8)));
typedef _Float16 f16x4 __attribute__((ext_vector_type(4)));
typedef float f32x4 __attribute__((ext_vector_type(4)));

__device__ __forceinline__ f16x8 ld_cvt(const float* __restrict__ p)
{
  float4 u = *reinterpret_cast<const float4*>(p);
  float4 v = *reinterpret_cast<const float4*>(p + 4);
  f16x8 h = {(_Float16)u.x, (_Float16)u.y, (_Float16)u.z, (_Float16)u.w,
             (_Float16)v.x, (_Float16)v.y, (_Float16)v.z, (_Float16)v.w};
  return h;
}

// ---------------------------------------------------------------------------
// K1: per-(b,h,side) fused projection + attention. 512 threads (8 waves).
// Phase 1 (projection GEMMs, K=512, operands direct from global):
//   Ktile[key256][d64] = X @ Wkv[h*64+d, side*512+:].T     (X = xv|xa rows b)
//   Vtile[key256][d64] = X @ Wkv[512+h*64+d, side*512+:].T
//   q[n64][d64]        = xmm_b @ Wq[h*64+d, :].T * 0.125
//   wave w: keyfrags (w>>1)*4+{0..3} x dfrags (w&1)*2+{0,1} (K and V share
//   X A-frags); q frags f = 2w, 2w+1.
// Acc -> swizzled LDS (R7-verified layouts: chunk ^ (row&7)); Vtile written
// transposed (C-rows = 4 consecutive keys -> contiguous f16x4).
// Phase 2 = R7 attention body (QK^T swapped, cross-wave softmax, PV), output
// per-side normalized to hv/ha.
// ---------------------------------------------------------------------------
__global__ __launch_bounds__(512) void fused_bh_kernel(
    const float* __restrict__ xmm, const float* __restrict__ xa,
    const float* __restrict__ xv, const float* __restrict__ Wq,
    const float* __restrict__ Wkv, float* __restrict__ hv,
    float* __restrict__ ha)
{
  __shared__ __align__(16) _Float16 smem[55552];   // 108.5 KB
  _Float16* Kl = smem;            // [256][64] swizzled   32 KB
  _Float16* Vl = smem + 16384;    // [64][256] (V^T)      32 KB
  _Float16* Ql = smem + 32768;    // [64][64]              8 KB
  _Float16* P  = smem + 36864;    // [64][256]            32 KB
  float* m_s  = (float*)(smem + 53248);   // [8][64]
  float* l_s  = m_s + 512;                // [8][64]
  float* Mtot = l_s + 512;                // [64]
  float* Ltot = Mtot + 64;                // [64]

  const int bid = blockIdx.x;     // b*16 + h*2 + side
  const int side = bid & 1;
  const int h = (bid >> 1) & 7;
  const int b = bid >> 4;

  const int tid = threadIdx.x;
  const int w = tid >> 6;         // wave 0..7
  const int lane = tid & 63;
  const int l15 = lane & 15;
  const int kg = lane >> 4;       // 0..3

  const float* X = (side ? xa : xv) + (size_t)b * 256 * 512;
  const float* xmm_b = xmm + (size_t)b * 64 * 512;

  // ---- phase 1: projections ----
  const int kgrp = (w >> 1) * 4;          // 4 key-frags
  const int dgrp = (w & 1) * 2;           // 2 d-frags
  const int qf0 = w * 2;                  // q frags qf0, qf0+1
  const int nfq = qf0 >> 2;
  const int dq0 = qf0 & 3, dq1 = (qf0 + 1) & 3;

  f32x4 ak[4][2] = {};
  f32x4 av[4][2] = {};
  f32x4 aq[2] = {};

  #pragma unroll 2
  for (int kk = 0; kk < 16; ++kk) {
    const int k0 = kk * 32 + kg * 8;
    f16x8 xf[4], wk[2], wvv[2];
    #pragma unroll
    for (int i = 0; i < 4; ++i)
      xf[i] = ld_cvt(&X[(size_t)((kgrp + i) * 16 + l15) * 512 + k0]);
    #pragma unroll
    for (int j = 0; j < 2; ++j) {
      const int d = (dgrp + j) * 16 + l15;
      wk[j]  = ld_cvt(&Wkv[(size_t)(h * 64 + d) * 1024 + side * 512 + k0]);
      wvv[j] = ld_cvt(&Wkv[(size_t)(512 + h * 64 + d) * 1024 + side * 512 + k0]);
    }
    f16x8 xq  = ld_cvt(&xmm_b[(size_t)(nfq * 16 + l15) * 512 + k0]);
    f16x8 wq0 = ld_cvt(&Wq[(size_t)(h * 64 + dq0 * 16 + l15) * 512 + k0]);
    f16x8 wq1 = ld_cvt(&Wq[(size_t)(h * 64 + dq1 * 16 + l15) * 512 + k0]);

    #pragma unroll
    for (int i = 0; i < 4; ++i)
      #pragma unroll
      for (int j = 0; j < 2; ++j) {
        ak[i][j] = __builtin_amdgcn_mfma_f32_16x16x32_f16(
            xf[i], wk[j], ak[i][j], 0, 0, 0);
        av[i][j] = __builtin_amdgcn_mfma_f32_16x16x32_f16(
            xf[i], wvv[j], av[i][j], 0, 0, 0);
      }
    aq[0] = __builtin_amdgcn_mfma_f32_16x16x32_f16(xq, wq0, aq[0], 0, 0, 0);
    aq[1] = __builtin_amdgcn_mfma_f32_16x16x32_f16(xq, wq1, aq[1], 0, 0, 0);
  }

  // ---- acc -> swizzled LDS (C/D layout: col=l15, row=kg*4+r) ----
  #pragma unroll
  for (int i = 0; i < 4; ++i)
    #pragma unroll
    for (int j = 0; j < 2; ++j) {
      const int d = (dgrp + j) * 16 + l15;
      const int dch = d >> 3;
      #pragma unroll
      for (int r = 0; r < 4; ++r) {
        const int key = (kgrp + i) * 16 + kg * 4 + r;
        Kl[key * 64 + ((dch ^ (key & 7)) * 8) + (d & 7)] =
            (_Float16)ak[i][j][r];
      }
      const int chv = (kgrp + i) * 2 + (kg >> 1);   // key-chunk of this frag
      f16x4 vv4 = {(_Float16)av[i][j][0], (_Float16)av[i][j][1],
                   (_Float16)av[i][j][2], (_Float16)av[i][j][3]};
      *reinterpret_cast<f16x4*>(
          &Vl[d * 256 + ((chv ^ (d & 7)) * 8) + (kg & 1) * 4]) = vv4;
    }
  {
    const int dqs[2] = {dq0 * 16 + l15, dq1 * 16 + l15};
    #pragma unroll
    for (int e = 0; e < 2; ++e) {
      const int dq = dqs[e];
      #pragma unroll
      for (int r = 0; r < 4; ++r) {
        const int n = nfq * 16 + kg * 4 + r;
        Ql[n * 64 + (((dq >> 3) ^ (n & 7)) * 8) + (dq & 7)] =
            (_Float16)(aq[e][r] * 0.125f);
      }
    }
  }
  __syncthreads();

  // ---- phase 2: attention (R7/R9-verified body) ----
  // QK^T: S^T[key][q] = mfma(K,Q), keys w*32 + kf*16 + l15
  f16x8 qb[4][2];
  #pragma unroll
  for (int qf = 0; qf < 4; ++qf)
    #pragma unroll
    for (int ks = 0; ks < 2; ++ks)
      qb[qf][ks] = *reinterpret_cast<const f16x8*>(
          &Ql[(qf * 16 + l15) * 64 + (((ks * 4 + kg) ^ (l15 & 7)) * 8)]);

  f32x4 st[2][4] = {};
  #pragma unroll
  for (int kf = 0; kf < 2; ++kf) {
    int krow = w * 32 + kf * 16 + l15;
    #pragma unroll
    for (int ks = 0; ks < 2; ++ks) {
      f16x8 af = *reinterpret_cast<const f16x8*>(
          &Kl[krow * 64 + (((ks * 4 + kg) ^ (l15 & 7)) * 8)]);
      #pragma unroll
      for (int qf = 0; qf < 4; ++qf)
        st[kf][qf] = __builtin_amdgcn_mfma_f32_16x16x32_f16(
            af, qb[qf][ks], st[kf][qf], 0, 0, 0);
    }
  }
  // st[kf][qf][r] = S[key=w*32+kf*16+4*kg+r][q=qf*16+l15]

  // per-wave max -> LDS -> global max over 8 waves
  float mx[4];
  #pragma unroll
  for (int qf = 0; qf < 4; ++qf) {
    float m = st[0][qf][0];
    #pragma unroll
    for (int kf = 0; kf < 2; ++kf)
      #pragma unroll
      for (int r = 0; r < 4; ++r) m = fmaxf(m, st[kf][qf][r]);
    m = fmaxf(m, __shfl_xor(m, 16));
    m = fmaxf(m, __shfl_xor(m, 32));
    mx[qf] = m;
  }
  if (kg == 0) {
    #pragma unroll
    for (int qf = 0; qf < 4; ++qf) m_s[w * 64 + qf * 16 + l15] = mx[qf];
  }
  __syncthreads();
  if (tid < 64) {
    float M = m_s[tid];
    #pragma unroll
    for (int w2 = 1; w2 < 8; ++w2) M = fmaxf(M, m_s[w2 * 64 + tid]);
    Mtot[tid] = M;
  }
  __syncthreads();

  // exp, partial sums, P -> swizzled LDS
  #pragma unroll
  for (int qf = 0; qf < 4; ++qf) {
    float M = Mtot[qf * 16 + l15];
    float ls = 0.f;
    #pragma unroll
    for (int kf = 0; kf < 2; ++kf)
      #pragma unroll
      for (int r = 0; r < 4; ++r) {
        float e = __expf(st[kf][qf][r] - M);
        st[kf][qf][r] = e;
        ls += e;
      }
    ls += __shfl_xor(ls, 16);
    ls += __shfl_xor(ls, 32);
    if (kg == 0) l_s[w * 64 + qf * 16 + l15] = ls;
    #pragma unroll
    for (int kf = 0; kf < 2; ++kf) {
      int q = qf * 16 + l15;
      int chunk = w * 4 + kf * 2 + (kg >> 1);
      f16x4 pk = {(_Float16)st[kf][qf][0], (_Float16)st[kf][qf][1],
                  (_Float16)st[kf][qf][2], (_Float16)st[kf][qf][3]};
      *reinterpret_cast<f16x4*>(
          &P[q * 256 + ((chunk ^ (q & 7)) * 8) + (kg & 1) * 4]) = pk;
    }
  }
  __syncthreads();
  if (tid < 64) {
    float L = l_s[tid];
    #pragma unroll
    for (int w2 = 1; w2 < 8; ++w2) L += l_s[w2 * 64 + tid];
    Ltot[tid] = L;
  }
  __syncthreads();

  // PV: wave owns (qf = w&3, d-frags 2*(w>>2)+{0,1}), all 256 keys
  const int qf = w & 3;
  const int d0 = (w >> 2) * 2;
  f32x4 oc[2] = {};
  #pragma unroll
  for (int ks = 0; ks < 8; ++ks) {
    f16x8 pa = *reinterpret_cast<const f16x8*>(
        &P[(qf * 16 + l15) * 256 + (((ks * 4 + kg) ^ (l15 & 7)) * 8)]);
    #pragma unroll
    for (int j = 0; j < 2; ++j) {
      int d = (d0 + j) * 16 + l15;
      f16x8 vb = *reinterpret_cast<const f16x8*>(
          &Vl[d * 256 + (((ks * 4 + kg) ^ (d & 7)) * 8)]);
      oc[j] = __builtin_amdgcn_mfma_f32_16x16x32_f16(pa, vb, oc[j], 0, 0, 0);
    }
  }

  float* houtS = side ? ha : hv;
  #pragma unroll
  for (int j = 0; j < 2; ++j)
    #pragma unroll
    for (int r = 0; r < 4; ++r) {
      int q = qf * 16 + kg * 4 + r;
      int d = (d0 + j) * 16 + l15;
      houtS[(size_t)(b * 64 + q) * 512 + h * 64 + d] =
          oc[j][r] * (1.0f / Ltot[q]);
    }
}

// ---------------------------------------------------------------------------
// K2: out = (hv + ha) @ Wproj.T + bproj. 64x64 MFMA tiles, 16 blocks x 256.
// ---------------------------------------------------------------------------
__device__ __forceinline__ void stage_sum_f16(
    const float* __restrict__ g, const float* __restrict__ g2, int ld,
    int base, int k0, _Float16* __restrict__ lds, int sr, int sq)
{
  const float* p = &g[(size_t)(base + sr) * ld + k0 + sq * 16];
  const float* p2 = g2 ? &g2[(size_t)(base + sr) * ld + k0 + sq * 16] : nullptr;
  float4 v[4];
  #pragma unroll
  for (int i = 0; i < 4; ++i) {
    v[i] = *reinterpret_cast<const float4*>(p + 4 * i);
    if (p2) {
      float4 u = *reinterpret_cast<const float4*>(p2 + 4 * i);
      v[i].x += u.x; v[i].y += u.y; v[i].z += u.z; v[i].w += u.w;
    }
  }
  f16x8 h0 = {(_Float16)v[0].x, (_Float16)v[0].y, (_Float16)v[0].z, (_Float16)v[0].w,
              (_Float16)v[1].x, (_Float16)v[1].y, (_Float16)v[1].z, (_Float16)v[1].w};
  f16x8 h1 = {(_Float16)v[2].x, (_Float16)v[2].y, (_Float16)v[2].z, (_Float16)v[2].w,
              (_Float16)v[3].x, (_Float16)v[3].y, (_Float16)v[3].z, (_Float16)v[3].w};
  int c0 = (sq * 2) ^ (sr & 7);
  int c1 = (sq * 2 + 1) ^ (sr & 7);
  *reinterpret_cast<f16x8*>(&lds[sr * 64 + c0 * 8]) = h0;
  *reinterpret_cast<f16x8*>(&lds[sr * 64 + c1 * 8]) = h1;
}

__global__ __launch_bounds__(256) void proj_out_kernel(
    const float* __restrict__ hv, const float* __restrict__ ha,
    const float* __restrict__ Wproj, const float* __restrict__ bproj,
    float* __restrict__ out)
{
  __shared__ _Float16 As[64 * 64];
  __shared__ _Float16 Ws[64 * 64];
  const int bm = (int)(blockIdx.x >> 3) * 64;
  const int bn = (int)(blockIdx.x & 7) * 64;
  const int tid = threadIdx.x;
  const int lane = tid & 63;
  const int w = tid >> 6;
  const int wm = w >> 1, wn = w & 1;
  const int sr = tid >> 2;
  const int sq = tid & 3;

  f32x4 acc[2][2] = {};
  const int cl = lane & 15;
  const int kg = lane >> 4;

  for (int k0 = 0; k0 < 512; k0 += 64) {
    __syncthreads();
    stage_sum_f16(hv, ha, 512, bm, k0, As, sr, sq);
    stage_sum_f16(Wproj, nullptr, 512, bn, k0, Ws, sr, sq);
    __syncthreads();
    #pragma unroll
    for (int ks = 0; ks < 2; ++ks) {
      f16x8 af[2], bf[2];
      #pragma unroll
      for (int mi = 0; mi < 2; ++mi) {
        int row = wm * 32 + mi * 16 + cl;
        int ch = (ks * 4 + kg) ^ (row & 7);
        af[mi] = *reinterpret_cast<const f16x8*>(&As[row * 64 + ch * 8]);
      }
      #pragma unroll
      for (int ni = 0; ni < 2; ++ni) {
        int col = wn * 32 + ni * 16 + cl;
        int ch = (ks * 4 + kg) ^ (col & 7);
        bf[ni] = *reinterpret_cast<const f16x8*>(&Ws[col * 64 + ch * 8]);
      }
      #pragma unroll
      for (int mi = 0; mi < 2; ++mi)
        #pragma unroll
        for (int ni = 0; ni < 2; ++ni)
          acc[mi][ni] = __builtin_amdgcn_mfma_f32_16x16x32_f16(
              af[mi], bf[ni], acc[mi][ni], 0, 0, 0);
    }
  }

  #pragma unroll
  for (int mi = 0; mi < 2; ++mi)
    #pragma unroll
    for (int ni = 0; ni < 2; ++ni) {
      int row0 = bm + wm * 32 + mi * 16 + kg * 4;
      int col = bn + wn * 32 + ni * 16 + cl;
      float bv = bproj[col];
      #pragma unroll
      for (int r = 0; r < 4; ++r)
        out[(size_t)(row0 + r) * 512 + col] = acc[mi][ni][r] + bv;
    }
}

extern "C" void kernel_launch(void* const* d_in, const int* in_sizes, int n_in,
                              void* d_out, int out_size, void* d_ws, size_t ws_size,
                              hipStream_t stream) {
  const float* xmm   = (const float*)d_in[0];  // [2,64,512]
  const float* xa    = (const float*)d_in[1];  // [2,256,512]
  const float* xv    = (const float*)d_in[2];  // [2,256,512]
  const float* Wq    = (const float*)d_in[3];  // [512,512]
  const float* Wkv   = (const float*)d_in[4];  // [1024,1024]
  const float* Wproj = (const float*)d_in[5];  // [512,512]
  const float* bproj = (const float*)d_in[6];  // [512]
  float* out = (float*)d_out;                  // [2,64,512]
  float* hv = (float*)d_ws;                    // [128][512] f32
  float* ha = hv + 65536;                      // [128][512] f32

  fused_bh_kernel<<<32, 512, 0, stream>>>(xmm, xa, xv, Wq, Wkv, hv, ha);
  proj_out_kernel<<<16, 256, 0, stream>>>(hv, ha, Wproj, bproj, out);
}

// Round 11
// 37.090 us; speedup vs baseline: 2.6470x; 2.6470x over previous
//
#include <hip/hip_runtime.h>

// B=2, N_mm=64, N_a=N_v=256, DIM=512, H=8, hd=64, scale=1/8.
// Factorized: softmax over (i,j) grid with logits Av_i+Aa_j, values vv_i+va_j
// = SUM of two independently-normalized 256-key attentions:
//   out = (Σ_i softmax_i(Av) vv_i) + (Σ_j softmax_j(Aa) va_j).
//
// Lessons baked in (measured R2-R10):
//  * MFMA operands ONLY from LDS via coalesced 16B/lane staging (scattered
//    per-lane strided global feeds = 96us kernel, R10).
//  * No slab handoff between kernels (scattered 2B stores + cross-kernel
//    flush ~ 25us, R7/R9); only contiguous f32 hv/ha crosses (free, R10).
//  * No persistent-kernel spin barriers (35us each, R6/R8).
// Structure: K1 = per-(b,h,side) fused projection+attention (32 blocks x 512
// thr, 136KB LDS); K2 = out-projection (16 blocks x 256 thr).

typedef _Float16 f16x8 __attribute__((ext_vector_type(8)));
typedef _Float16 f16x4 __attribute__((ext_vector_type(4)));
typedef float f32x4 __attribute__((ext_vector_type(4)));

// ---------------------------------------------------------------------------
// K1. LDS map (f16 units), 69632 = 136 KB:
//   [0)      Xs [256 key][64 k] swizzled  32KB   -> P [64 q][256 key] phase 2
//   [16384)  Ws [256 row][64 k] swizzled  32KB   -> m_s/l_s/Mtot/Ltot
//            rows 0-63 WkvK(d), 64-127 WkvV(d), 128-191 Wq(d), 192-255 xmm(n)
//   [32768)  Kl [256 key][64 d] swizzled  32KB
//   [49152)  Vl [64 d][256 key] swizzled  32KB   (V^T)
//   [65536)  Ql [64 n][64 d]    swizzled   8KB
// Phase 1: 8 K-steps (BK=64). Per step: reg->LDS store, barrier, issue next
// step's global loads (latency hides under MFMA), MFMA from LDS, barrier.
// Wave w owns K/V key-frags {2w,2w+1} x all 4 d-frags, q-frags {2w,2w+1}.
// Phase 2: R7/R10-verified attention body; per-side normalized out to hv/ha.
// ---------------------------------------------------------------------------
__global__ __launch_bounds__(512) void fused_bh_kernel(
    const float* __restrict__ xmm, const float* __restrict__ xa,
    const float* __restrict__ xv, const float* __restrict__ Wq,
    const float* __restrict__ Wkv, float* __restrict__ hv,
    float* __restrict__ ha)
{
  __shared__ __align__(16) _Float16 smem[69632];
  _Float16* Xs = smem;
  _Float16* Ws = smem + 16384;
  _Float16* Kl = smem + 32768;
  _Float16* Vl = smem + 49152;
  _Float16* Ql = smem + 65536;
  _Float16* P  = smem;                       // phase-2 overlay of Xs
  float* m_s  = (float*)(smem + 16384);      // [8][64] overlay of Ws
  float* l_s  = m_s + 512;                   // [8][64]
  float* Mtot = l_s + 512;                   // [64]
  float* Ltot = Mtot + 64;                   // [64]

  const int bid = blockIdx.x;     // b*16 + h*2 + side
  const int side = bid & 1;
  const int h = (bid >> 1) & 7;
  const int b = bid >> 4;

  const int tid = threadIdx.x;
  const int w = tid >> 6;         // wave 0..7
  const int lane = tid & 63;
  const int l15 = lane & 15;
  const int kg = lane >> 4;       // 0..3

  const float* X = (side ? xa : xv) + (size_t)b * 256 * 512;
  const float* xmm_b = xmm + (size_t)b * 64 * 512;

  // per-thread staging geometry: 4 X-chunks + 4 W-chunks of f16x8
  const int srow = tid >> 3;      // 0..63 (row offset within each 64-row band)
  const int sc = tid & 7;         // chunk 0..7 (32B of fp32 source)

  // global row pointers (k-invariant part)
  const float* gx[4];
  #pragma unroll
  for (int i = 0; i < 4; ++i)
    gx[i] = X + (size_t)(i * 64 + srow) * 512 + sc * 8;
  const float* gw[4];
  gw[0] = Wkv + (size_t)(h * 64 + srow) * 1024 + side * 512 + sc * 8;
  gw[1] = Wkv + (size_t)(512 + h * 64 + srow) * 1024 + side * 512 + sc * 8;
  gw[2] = Wq + (size_t)(h * 64 + srow) * 512 + sc * 8;
  gw[3] = xmm_b + (size_t)srow * 512 + sc * 8;

  f32x4 ak[2][4] = {};            // K acc [e][df]
  f32x4 avv[2][4] = {};           // V acc
  f32x4 aq[2] = {};               // q acc
  const int nf = w >> 1;          // q A-frag row band

  float4 rx[2][16];               // double-buffered staging regs (static idx)

  // prologue: load step 0
  #pragma unroll
  for (int i = 0; i < 4; ++i) {
    rx[0][2 * i]     = *reinterpret_cast<const float4*>(gx[i]);
    rx[0][2 * i + 1] = *reinterpret_cast<const float4*>(gx[i] + 4);
    rx[0][8 + 2 * i]     = *reinterpret_cast<const float4*>(gw[i]);
    rx[0][8 + 2 * i + 1] = *reinterpret_cast<const float4*>(gw[i] + 4);
  }

  #pragma unroll
  for (int s = 0; s < 8; ++s) {
    const int cur = s & 1;
    __syncthreads();              // previous MFMA done reading LDS
    // ---- reg -> swizzled f16 LDS
    #pragma unroll
    for (int i = 0; i < 4; ++i) {
      float4 a = rx[cur][2 * i], bq = rx[cur][2 * i + 1];
      f16x8 hx = {(_Float16)a.x, (_Float16)a.y, (_Float16)a.z, (_Float16)a.w,
                  (_Float16)bq.x, (_Float16)bq.y, (_Float16)bq.z, (_Float16)bq.w};
      int row = i * 64 + srow;
      *reinterpret_cast<f16x8*>(&Xs[row * 64 + ((sc ^ (row & 7)) * 8)]) = hx;
      float4 c = rx[cur][8 + 2 * i], d = rx[cur][8 + 2 * i + 1];
      f16x8 hw = {(_Float16)c.x, (_Float16)c.y, (_Float16)c.z, (_Float16)c.w,
                  (_Float16)d.x, (_Float16)d.y, (_Float16)d.z, (_Float16)d.w};
      *reinterpret_cast<f16x8*>(&Ws[row * 64 + ((sc ^ (row & 7)) * 8)]) = hw;
    }
    __syncthreads();              // LDS visible
    // ---- issue next step's global loads (hide latency under MFMA)
    if (s < 7) {
      const int nxt = cur ^ 1;
      const int ko = (s + 1) * 64;
      #pragma unroll
      for (int i = 0; i < 4; ++i) {
        rx[nxt][2 * i]     = *reinterpret_cast<const float4*>(gx[i] + ko);
        rx[nxt][2 * i + 1] = *reinterpret_cast<const float4*>(gx[i] + ko + 4);
        rx[nxt][8 + 2 * i]     = *reinterpret_cast<const float4*>(gw[i] + ko);
        rx[nxt][8 + 2 * i + 1] = *reinterpret_cast<const float4*>(gw[i] + ko + 4);
      }
    }
    // ---- MFMA from LDS (ks inner to cap operand liveness)
    #pragma unroll
    for (int ks = 0; ks < 2; ++ks) {
      const int cc = ks * 4 + kg;
      f16x8 xaf[2];
      #pragma unroll
      for (int e = 0; e < 2; ++e) {
        int row = (2 * w + e) * 16 + l15;
        xaf[e] = *reinterpret_cast<const f16x8*>(
            &Xs[row * 64 + ((cc ^ (row & 7)) * 8)]);
      }
      f16x8 xqa;
      {
        int row = 192 + nf * 16 + l15;
        xqa = *reinterpret_cast<const f16x8*>(
            &Ws[row * 64 + ((cc ^ (row & 7)) * 8)]);
      }
      #pragma unroll
      for (int df = 0; df < 4; ++df) {
        int rk = df * 16 + l15;
        f16x8 wkB = *reinterpret_cast<const f16x8*>(
            &Ws[rk * 64 + ((cc ^ (rk & 7)) * 8)]);
        int rv = 64 + df * 16 + l15;
        f16x8 wvB = *reinterpret_cast<const f16x8*>(
            &Ws[rv * 64 + ((cc ^ (rv & 7)) * 8)]);
        #pragma unroll
        for (int e = 0; e < 2; ++e) {
          ak[e][df] = __builtin_amdgcn_mfma_f32_16x16x32_f16(
              xaf[e], wkB, ak[e][df], 0, 0, 0);
          avv[e][df] = __builtin_amdgcn_mfma_f32_16x16x32_f16(
              xaf[e], wvB, avv[e][df], 0, 0, 0);
        }
      }
      #pragma unroll
      for (int e = 0; e < 2; ++e) {
        int dq = ((2 * w + e) & 3) * 16 + l15;
        int rq = 128 + dq;
        f16x8 wqB = *reinterpret_cast<const f16x8*>(
            &Ws[rq * 64 + ((cc ^ (rq & 7)) * 8)]);
        aq[e] = __builtin_amdgcn_mfma_f32_16x16x32_f16(
            xqa, wqB, aq[e], 0, 0, 0);
      }
    }
  }

  // ---- epilogue: fragments -> Kl / Vl(transposed) / Ql (R10-verified maps)
  #pragma unroll
  for (int e = 0; e < 2; ++e) {
    const int kf = 2 * w + e;
    #pragma unroll
    for (int df = 0; df < 4; ++df) {
      const int d = df * 16 + l15;
      const int dch = d >> 3;
      #pragma unroll
      for (int r = 0; r < 4; ++r) {
        const int key = kf * 16 + kg * 4 + r;
        Kl[key * 64 + ((dch ^ (key & 7)) * 8) + (d & 7)] =
            (_Float16)ak[e][df][r];
      }
      const int chv = kf * 2 + (kg >> 1);
      f16x4 vv4 = {(_Float16)avv[e][df][0], (_Float16)avv[e][df][1],
                   (_Float16)avv[e][df][2], (_Float16)avv[e][df][3]};
      *reinterpret_cast<f16x4*>(
          &Vl[d * 256 + ((chv ^ (d & 7)) * 8) + (kg & 1) * 4]) = vv4;
    }
    const int dq = ((2 * w + e) & 3) * 16 + l15;
    #pragma unroll
    for (int r = 0; r < 4; ++r) {
      const int n = nf * 16 + kg * 4 + r;
      Ql[n * 64 + (((dq >> 3) ^ (n & 7)) * 8) + (dq & 7)] =
          (_Float16)(aq[e][r] * 0.125f);
    }
  }
  __syncthreads();

  // ---- phase 2: attention (R7/R10-verified body) ----
  f16x8 qb[4][2];
  #pragma unroll
  for (int qf = 0; qf < 4; ++qf)
    #pragma unroll
    for (int ks = 0; ks < 2; ++ks)
      qb[qf][ks] = *reinterpret_cast<const f16x8*>(
          &Ql[(qf * 16 + l15) * 64 + (((ks * 4 + kg) ^ (l15 & 7)) * 8)]);

  f32x4 st[2][4] = {};
  #pragma unroll
  for (int kf = 0; kf < 2; ++kf) {
    int krow = w * 32 + kf * 16 + l15;
    #pragma unroll
    for (int ks = 0; ks < 2; ++ks) {
      f16x8 af = *reinterpret_cast<const f16x8*>(
          &Kl[krow * 64 + (((ks * 4 + kg) ^ (l15 & 7)) * 8)]);
      #pragma unroll
      for (int qf = 0; qf < 4; ++qf)
        st[kf][qf] = __builtin_amdgcn_mfma_f32_16x16x32_f16(
            af, qb[qf][ks], st[kf][qf], 0, 0, 0);
    }
  }
  // st[kf][qf][r] = S[key=w*32+kf*16+4*kg+r][q=qf*16+l15]

  float mx[4];
  #pragma unroll
  for (int qf = 0; qf < 4; ++qf) {
    float m = st[0][qf][0];
    #pragma unroll
    for (int kf = 0; kf < 2; ++kf)
      #pragma unroll
      for (int r = 0; r < 4; ++r) m = fmaxf(m, st[kf][qf][r]);
    m = fmaxf(m, __shfl_xor(m, 16));
    m = fmaxf(m, __shfl_xor(m, 32));
    mx[qf] = m;
  }
  if (kg == 0) {
    #pragma unroll
    for (int qf = 0; qf < 4; ++qf) m_s[w * 64 + qf * 16 + l15] = mx[qf];
  }
  __syncthreads();
  if (tid < 64) {
    float M = m_s[tid];
    #pragma unroll
    for (int w2 = 1; w2 < 8; ++w2) M = fmaxf(M, m_s[w2 * 64 + tid]);
    Mtot[tid] = M;
  }
  __syncthreads();

  #pragma unroll
  for (int qf = 0; qf < 4; ++qf) {
    float M = Mtot[qf * 16 + l15];
    float ls = 0.f;
    #pragma unroll
    for (int kf = 0; kf < 2; ++kf)
      #pragma unroll
      for (int r = 0; r < 4; ++r) {
        float e = __expf(st[kf][qf][r] - M);
        st[kf][qf][r] = e;
        ls += e;
      }
    ls += __shfl_xor(ls, 16);
    ls += __shfl_xor(ls, 32);
    if (kg == 0) l_s[w * 64 + qf * 16 + l15] = ls;
    #pragma unroll
    for (int kf = 0; kf < 2; ++kf) {
      int q = qf * 16 + l15;
      int chunk = w * 4 + kf * 2 + (kg >> 1);
      f16x4 pk = {(_Float16)st[kf][qf][0], (_Float16)st[kf][qf][1],
                  (_Float16)st[kf][qf][2], (_Float16)st[kf][qf][3]};
      *reinterpret_cast<f16x4*>(
          &P[q * 256 + ((chunk ^ (q & 7)) * 8) + (kg & 1) * 4]) = pk;
    }
  }
  __syncthreads();
  if (tid < 64) {
    float L = l_s[tid];
    #pragma unroll
    for (int w2 = 1; w2 < 8; ++w2) L += l_s[w2 * 64 + tid];
    Ltot[tid] = L;
  }
  __syncthreads();

  // PV: wave owns (qf = w&3, d-frags 2*(w>>2)+{0,1}), all 256 keys
  const int qf = w & 3;
  const int d0 = (w >> 2) * 2;
  f32x4 oc[2] = {};
  #pragma unroll
  for (int ks = 0; ks < 8; ++ks) {
    f16x8 pa = *reinterpret_cast<const f16x8*>(
        &P[(qf * 16 + l15) * 256 + (((ks * 4 + kg) ^ (l15 & 7)) * 8)]);
    #pragma unroll
    for (int j = 0; j < 2; ++j) {
      int d = (d0 + j) * 16 + l15;
      f16x8 vb = *reinterpret_cast<const f16x8*>(
          &Vl[d * 256 + (((ks * 4 + kg) ^ (d & 7)) * 8)]);
      oc[j] = __builtin_amdgcn_mfma_f32_16x16x32_f16(pa, vb, oc[j], 0, 0, 0);
    }
  }

  float* houtS = side ? ha : hv;
  #pragma unroll
  for (int j = 0; j < 2; ++j)
    #pragma unroll
    for (int r = 0; r < 4; ++r) {
      int q = qf * 16 + kg * 4 + r;
      int d = (d0 + j) * 16 + l15;
      houtS[(size_t)(b * 64 + q) * 512 + h * 64 + d] =
          oc[j][r] * (1.0f / Ltot[q]);
    }
}

// ---------------------------------------------------------------------------
// K2: out = (hv + ha) @ Wproj.T + bproj. 64x64 MFMA tiles, 16 blocks x 256.
// ---------------------------------------------------------------------------
__device__ __forceinline__ void stage_sum_f16(
    const float* __restrict__ g, const float* __restrict__ g2, int ld,
    int base, int k0, _Float16* __restrict__ lds, int sr, int sq)
{
  const float* p = &g[(size_t)(base + sr) * ld + k0 + sq * 16];
  const float* p2 = g2 ? &g2[(size_t)(base + sr) * ld + k0 + sq * 16] : nullptr;
  float4 v[4];
  #pragma unroll
  for (int i = 0; i < 4; ++i) {
    v[i] = *reinterpret_cast<const float4*>(p + 4 * i);
    if (p2) {
      float4 u = *reinterpret_cast<const float4*>(p2 + 4 * i);
      v[i].x += u.x; v[i].y += u.y; v[i].z += u.z; v[i].w += u.w;
    }
  }
  f16x8 h0 = {(_Float16)v[0].x, (_Float16)v[0].y, (_Float16)v[0].z, (_Float16)v[0].w,
              (_Float16)v[1].x, (_Float16)v[1].y, (_Float16)v[1].z, (_Float16)v[1].w};
  f16x8 h1 = {(_Float16)v[2].x, (_Float16)v[2].y, (_Float16)v[2].z, (_Float16)v[2].w,
              (_Float16)v[3].x, (_Float16)v[3].y, (_Float16)v[3].z, (_Float16)v[3].w};
  int c0 = (sq * 2) ^ (sr & 7);
  int c1 = (sq * 2 + 1) ^ (sr & 7);
  *reinterpret_cast<f16x8*>(&lds[sr * 64 + c0 * 8]) = h0;
  *reinterpret_cast<f16x8*>(&lds[sr * 64 + c1 * 8]) = h1;
}

__global__ __launch_bounds__(256) void proj_out_kernel(
    const float* __restrict__ hv, const float* __restrict__ ha,
    const float* __restrict__ Wproj, const float* __restrict__ bproj,
    float* __restrict__ out)
{
  __shared__ _Float16 As[64 * 64];
  __shared__ _Float16 Ws[64 * 64];
  const int bm = (int)(blockIdx.x >> 3) * 64;
  const int bn = (int)(blockIdx.x & 7) * 64;
  const int tid = threadIdx.x;
  const int lane = tid & 63;
  const int w = tid >> 6;
  const int wm = w >> 1, wn = w & 1;
  const int sr = tid >> 2;
  const int sq = tid & 3;

  f32x4 acc[2][2] = {};
  const int cl = lane & 15;
  const int kg = lane >> 4;

  for (int k0 = 0; k0 < 512; k0 += 64) {
    __syncthreads();
    stage_sum_f16(hv, ha, 512, bm, k0, As, sr, sq);
    stage_sum_f16(Wproj, nullptr, 512, bn, k0, Ws, sr, sq);
    __syncthreads();
    #pragma unroll
    for (int ks = 0; ks < 2; ++ks) {
      f16x8 af[2], bf[2];
      #pragma unroll
      for (int mi = 0; mi < 2; ++mi) {
        int row = wm * 32 + mi * 16 + cl;
        int ch = (ks * 4 + kg) ^ (row & 7);
        af[mi] = *reinterpret_cast<const f16x8*>(&As[row * 64 + ch * 8]);
      }
      #pragma unroll
      for (int ni = 0; ni < 2; ++ni) {
        int col = wn * 32 + ni * 16 + cl;
        int ch = (ks * 4 + kg) ^ (col & 7);
        bf[ni] = *reinterpret_cast<const f16x8*>(&Ws[col * 64 + ch * 8]);
      }
      #pragma unroll
      for (int mi = 0; mi < 2; ++mi)
        #pragma unroll
        for (int ni = 0; ni < 2; ++ni)
          acc[mi][ni] = __builtin_amdgcn_mfma_f32_16x16x32_f16(
              af[mi], bf[ni], acc[mi][ni], 0, 0, 0);
    }
  }

  #pragma unroll
  for (int mi = 0; mi < 2; ++mi)
    #pragma unroll
    for (int ni = 0; ni < 2; ++ni) {
      int row0 = bm + wm * 32 + mi * 16 + kg * 4;
      int col = bn + wn * 32 + ni * 16 + cl;
      float bv = bproj[col];
      #pragma unroll
      for (int r = 0; r < 4; ++r)
        out[(size_t)(row0 + r) * 512 + col] = acc[mi][ni][r] + bv;
    }
}

extern "C" void kernel_launch(void* const* d_in, const int* in_sizes, int n_in,
                              void* d_out, int out_size, void* d_ws, size_t ws_size,
                              hipStream_t stream) {
  const float* xmm   = (const float*)d_in[0];  // [2,64,512]
  const float* xa    = (const float*)d_in[1];  // [2,256,512]
  const float* xv    = (const float*)d_in[2];  // [2,256,512]
  const float* Wq    = (const float*)d_in[3];  // [512,512]
  const float* Wkv   = (const float*)d_in[4];  // [1024,1024]
  const float* Wproj = (const float*)d_in[5];  // [512,512]
  const float* bproj = (const float*)d_in[6];  // [512]
  float* out = (float*)d_out;                  // [2,64,512]
  float* hv = (float*)d_ws;                    // [128][512] f32
  float* ha = hv + 65536;                      // [128][512] f32

  fused_bh_kernel<<<32, 512, 0, stream>>>(xmm, xa, xv, Wq, Wkv, hv, ha);
  proj_out_kernel<<<16, 256, 0, stream>>>(hv, ha, Wproj, bproj, out);
}

// Round 12
// 36.714 us; speedup vs baseline: 2.6741x; 1.0102x over previous
//
#include <hip/hip_runtime.h>

// B=2, N_mm=64, N_a=N_v=256, DIM=512, H=8, hd=64, scale=1/8.
// Factorized: softmax over (i,j) grid with logits Av_i+Aa_j, values vv_i+va_j
// = SUM of two independently-normalized 256-key attentions:
//   out = (Σ_i softmax_i(Av) vv_i) + (Σ_j softmax_j(Aa) va_j).
//
// Lessons baked in (measured R2-R11):
//  * MFMA operands ONLY from LDS via coalesced staging (R10: scattered = 96us)
//  * No slab handoff between kernels (R7/R9: ~25us); contiguous hv/ha is free
//  * No persistent-kernel spin barriers (R6/R8: ~35us each)
//  * R11: VGPR_Count=96 => staging buffers SPILLED to scratch (45us kernel).
//    Fix: __launch_bounds__(512,2) for a 256-VGPR budget (2 waves/SIMD is all
//    our 32-block grid can use anyway) + single-buffered rx[16].
// Structure: K1 = per-(b,h,side) fused projection+attention (32 blocks x 512
// thr, 136KB LDS); K2 = out-projection (16 blocks x 256 thr).

typedef _Float16 f16x8 __attribute__((ext_vector_type(8)));
typedef _Float16 f16x4 __attribute__((ext_vector_type(4)));
typedef float f32x4 __attribute__((ext_vector_type(4)));

// ---------------------------------------------------------------------------
// K1. LDS map (f16 units), 69632 = 136 KB:
//   [0)      Xs [256 key][64 k] swizzled  32KB   -> P [64 q][256 key] phase 2
//   [16384)  Ws [256 row][64 k] swizzled  32KB   -> m_s/l_s/Mtot/Ltot
//            rows 0-63 WkvK(d), 64-127 WkvV(d), 128-191 Wq(d), 192-255 xmm(n)
//   [32768)  Kl [256 key][64 d] swizzled  32KB
//   [49152)  Vl [64 d][256 key] swizzled  32KB   (V^T)
//   [65536)  Ql [64 n][64 d]    swizzled   8KB
// Phase 1: 8 K-steps (BK=64). Per step: reg->LDS store, barrier, issue next
// step's global loads (latency hides under MFMA), MFMA from LDS, barrier.
// Wave w owns K/V key-frags {2w,2w+1} x all 4 d-frags, q-frags {2w,2w+1}.
// Phase 2: R7/R10-verified attention body; per-side normalized out to hv/ha.
// ---------------------------------------------------------------------------
__global__ __launch_bounds__(512, 2) void fused_bh_kernel(
    const float* __restrict__ xmm, const float* __restrict__ xa,
    const float* __restrict__ xv, const float* __restrict__ Wq,
    const float* __restrict__ Wkv, float* __restrict__ hv,
    float* __restrict__ ha)
{
  __shared__ __align__(16) _Float16 smem[69632];
  _Float16* Xs = smem;
  _Float16* Ws = smem + 16384;
  _Float16* Kl = smem + 32768;
  _Float16* Vl = smem + 49152;
  _Float16* Ql = smem + 65536;
  _Float16* P  = smem;                       // phase-2 overlay of Xs
  float* m_s  = (float*)(smem + 16384);      // [8][64] overlay of Ws
  float* l_s  = m_s + 512;                   // [8][64]
  float* Mtot = l_s + 512;                   // [64]
  float* Ltot = Mtot + 64;                   // [64]

  const int bid = blockIdx.x;     // b*16 + h*2 + side
  const int side = bid & 1;
  const int h = (bid >> 1) & 7;
  const int b = bid >> 4;

  const int tid = threadIdx.x;
  const int w = tid >> 6;         // wave 0..7
  const int lane = tid & 63;
  const int l15 = lane & 15;
  const int kg = lane >> 4;       // 0..3

  const float* X = (side ? xa : xv) + (size_t)b * 256 * 512;
  const float* xmm_b = xmm + (size_t)b * 64 * 512;

  // per-thread staging geometry: 4 X-chunks + 4 W-chunks of f16x8
  const int srow = tid >> 3;      // 0..63 (row offset within each 64-row band)
  const int sc = tid & 7;         // chunk 0..7 (32B of fp32 source)

  // global row pointers (k-invariant part)
  const float* gx[4];
  #pragma unroll
  for (int i = 0; i < 4; ++i)
    gx[i] = X + (size_t)(i * 64 + srow) * 512 + sc * 8;
  const float* gw[4];
  gw[0] = Wkv + (size_t)(h * 64 + srow) * 1024 + side * 512 + sc * 8;
  gw[1] = Wkv + (size_t)(512 + h * 64 + srow) * 1024 + side * 512 + sc * 8;
  gw[2] = Wq + (size_t)(h * 64 + srow) * 512 + sc * 8;
  gw[3] = xmm_b + (size_t)srow * 512 + sc * 8;

  f32x4 ak[2][4] = {};            // K acc [e][df]
  f32x4 avv[2][4] = {};           // V acc
  f32x4 aq[2] = {};               // q acc
  const int nf = w >> 1;          // q A-frag row band

  float4 rx[16];                  // SINGLE-buffered staging regs (static idx)

  // prologue: load step 0
  #pragma unroll
  for (int i = 0; i < 4; ++i) {
    rx[2 * i]     = *reinterpret_cast<const float4*>(gx[i]);
    rx[2 * i + 1] = *reinterpret_cast<const float4*>(gx[i] + 4);
    rx[8 + 2 * i]     = *reinterpret_cast<const float4*>(gw[i]);
    rx[8 + 2 * i + 1] = *reinterpret_cast<const float4*>(gw[i] + 4);
  }

  #pragma unroll
  for (int s = 0; s < 8; ++s) {
    __syncthreads();              // previous MFMA done reading LDS
    // ---- reg -> swizzled f16 LDS (consumes rx; safe to refill after)
    #pragma unroll
    for (int i = 0; i < 4; ++i) {
      float4 a = rx[2 * i], bq = rx[2 * i + 1];
      f16x8 hx = {(_Float16)a.x, (_Float16)a.y, (_Float16)a.z, (_Float16)a.w,
                  (_Float16)bq.x, (_Float16)bq.y, (_Float16)bq.z, (_Float16)bq.w};
      int row = i * 64 + srow;
      *reinterpret_cast<f16x8*>(&Xs[row * 64 + ((sc ^ (row & 7)) * 8)]) = hx;
      float4 c = rx[8 + 2 * i], d = rx[8 + 2 * i + 1];
      f16x8 hw = {(_Float16)c.x, (_Float16)c.y, (_Float16)c.z, (_Float16)c.w,
                  (_Float16)d.x, (_Float16)d.y, (_Float16)d.z, (_Float16)d.w};
      *reinterpret_cast<f16x8*>(&Ws[row * 64 + ((sc ^ (row & 7)) * 8)]) = hw;
    }
    __syncthreads();              // LDS visible
    // ---- issue next step's global loads (hide latency under MFMA)
    if (s < 7) {
      const int ko = (s + 1) * 64;
      #pragma unroll
      for (int i = 0; i < 4; ++i) {
        rx[2 * i]     = *reinterpret_cast<const float4*>(gx[i] + ko);
        rx[2 * i + 1] = *reinterpret_cast<const float4*>(gx[i] + ko + 4);
        rx[8 + 2 * i]     = *reinterpret_cast<const float4*>(gw[i] + ko);
        rx[8 + 2 * i + 1] = *reinterpret_cast<const float4*>(gw[i] + ko + 4);
      }
    }
    // ---- MFMA from LDS (ks inner to cap operand liveness)
    #pragma unroll
    for (int ks = 0; ks < 2; ++ks) {
      const int cc = ks * 4 + kg;
      f16x8 xaf[2];
      #pragma unroll
      for (int e = 0; e < 2; ++e) {
        int row = (2 * w + e) * 16 + l15;
        xaf[e] = *reinterpret_cast<const f16x8*>(
            &Xs[row * 64 + ((cc ^ (row & 7)) * 8)]);
      }
      f16x8 xqa;
      {
        int row = 192 + nf * 16 + l15;
        xqa = *reinterpret_cast<const f16x8*>(
            &Ws[row * 64 + ((cc ^ (row & 7)) * 8)]);
      }
      #pragma unroll
      for (int df = 0; df < 4; ++df) {
        int rk = df * 16 + l15;
        f16x8 wkB = *reinterpret_cast<const f16x8*>(
            &Ws[rk * 64 + ((cc ^ (rk & 7)) * 8)]);
        int rv = 64 + df * 16 + l15;
        f16x8 wvB = *reinterpret_cast<const f16x8*>(
            &Ws[rv * 64 + ((cc ^ (rv & 7)) * 8)]);
        #pragma unroll
        for (int e = 0; e < 2; ++e) {
          ak[e][df] = __builtin_amdgcn_mfma_f32_16x16x32_f16(
              xaf[e], wkB, ak[e][df], 0, 0, 0);
          avv[e][df] = __builtin_amdgcn_mfma_f32_16x16x32_f16(
              xaf[e], wvB, avv[e][df], 0, 0, 0);
        }
      }
      #pragma unroll
      for (int e = 0; e < 2; ++e) {
        int dq = ((2 * w + e) & 3) * 16 + l15;
        int rq = 128 + dq;
        f16x8 wqB = *reinterpret_cast<const f16x8*>(
            &Ws[rq * 64 + ((cc ^ (rq & 7)) * 8)]);
        aq[e] = __builtin_amdgcn_mfma_f32_16x16x32_f16(
            xqa, wqB, aq[e], 0, 0, 0);
      }
    }
  }

  // ---- epilogue: fragments -> Kl / Vl(transposed) / Ql (R10-verified maps)
  #pragma unroll
  for (int e = 0; e < 2; ++e) {
    const int kf = 2 * w + e;
    #pragma unroll
    for (int df = 0; df < 4; ++df) {
      const int d = df * 16 + l15;
      const int dch = d >> 3;
      #pragma unroll
      for (int r = 0; r < 4; ++r) {
        const int key = kf * 16 + kg * 4 + r;
        Kl[key * 64 + ((dch ^ (key & 7)) * 8) + (d & 7)] =
            (_Float16)ak[e][df][r];
      }
      const int chv = kf * 2 + (kg >> 1);
      f16x4 vv4 = {(_Float16)avv[e][df][0], (_Float16)avv[e][df][1],
                   (_Float16)avv[e][df][2], (_Float16)avv[e][df][3]};
      *reinterpret_cast<f16x4*>(
          &Vl[d * 256 + ((chv ^ (d & 7)) * 8) + (kg & 1) * 4]) = vv4;
    }
    const int dq = ((2 * w + e) & 3) * 16 + l15;
    #pragma unroll
    for (int r = 0; r < 4; ++r) {
      const int n = nf * 16 + kg * 4 + r;
      Ql[n * 64 + (((dq >> 3) ^ (n & 7)) * 8) + (dq & 7)] =
          (_Float16)(aq[e][r] * 0.125f);
    }
  }
  __syncthreads();

  // ---- phase 2: attention (R7/R10-verified body) ----
  f16x8 qb[4][2];
  #pragma unroll
  for (int qf = 0; qf < 4; ++qf)
    #pragma unroll
    for (int ks = 0; ks < 2; ++ks)
      qb[qf][ks] = *reinterpret_cast<const f16x8*>(
          &Ql[(qf * 16 + l15) * 64 + (((ks * 4 + kg) ^ (l15 & 7)) * 8)]);

  f32x4 st[2][4] = {};
  #pragma unroll
  for (int kf = 0; kf < 2; ++kf) {
    int krow = w * 32 + kf * 16 + l15;
    #pragma unroll
    for (int ks = 0; ks < 2; ++ks) {
      f16x8 af = *reinterpret_cast<const f16x8*>(
          &Kl[krow * 64 + (((ks * 4 + kg) ^ (l15 & 7)) * 8)]);
      #pragma unroll
      for (int qf = 0; qf < 4; ++qf)
        st[kf][qf] = __builtin_amdgcn_mfma_f32_16x16x32_f16(
            af, qb[qf][ks], st[kf][qf], 0, 0, 0);
    }
  }
  // st[kf][qf][r] = S[key=w*32+kf*16+4*kg+r][q=qf*16+l15]

  float mx[4];
  #pragma unroll
  for (int qf = 0; qf < 4; ++qf) {
    float m = st[0][qf][0];
    #pragma unroll
    for (int kf = 0; kf < 2; ++kf)
      #pragma unroll
      for (int r = 0; r < 4; ++r) m = fmaxf(m, st[kf][qf][r]);
    m = fmaxf(m, __shfl_xor(m, 16));
    m = fmaxf(m, __shfl_xor(m, 32));
    mx[qf] = m;
  }
  if (kg == 0) {
    #pragma unroll
    for (int qf = 0; qf < 4; ++qf) m_s[w * 64 + qf * 16 + l15] = mx[qf];
  }
  __syncthreads();
  if (tid < 64) {
    float M = m_s[tid];
    #pragma unroll
    for (int w2 = 1; w2 < 8; ++w2) M = fmaxf(M, m_s[w2 * 64 + tid]);
    Mtot[tid] = M;
  }
  __syncthreads();

  #pragma unroll
  for (int qf = 0; qf < 4; ++qf) {
    float M = Mtot[qf * 16 + l15];
    float ls = 0.f;
    #pragma unroll
    for (int kf = 0; kf < 2; ++kf)
      #pragma unroll
      for (int r = 0; r < 4; ++r) {
        float e = __expf(st[kf][qf][r] - M);
        st[kf][qf][r] = e;
        ls += e;
      }
    ls += __shfl_xor(ls, 16);
    ls += __shfl_xor(ls, 32);
    if (kg == 0) l_s[w * 64 + qf * 16 + l15] = ls;
    #pragma unroll
    for (int kf = 0; kf < 2; ++kf) {
      int q = qf * 16 + l15;
      int chunk = w * 4 + kf * 2 + (kg >> 1);
      f16x4 pk = {(_Float16)st[kf][qf][0], (_Float16)st[kf][qf][1],
                  (_Float16)st[kf][qf][2], (_Float16)st[kf][qf][3]};
      *reinterpret_cast<f16x4*>(
          &P[q * 256 + ((chunk ^ (q & 7)) * 8) + (kg & 1) * 4]) = pk;
    }
  }
  __syncthreads();
  if (tid < 64) {
    float L = l_s[tid];
    #pragma unroll
    for (int w2 = 1; w2 < 8; ++w2) L += l_s[w2 * 64 + tid];
    Ltot[tid] = L;
  }
  __syncthreads();

  // PV: wave owns (qf = w&3, d-frags 2*(w>>2)+{0,1}), all 256 keys
  const int qf = w & 3;
  const int d0 = (w >> 2) * 2;
  f32x4 oc[2] = {};
  #pragma unroll
  for (int ks = 0; ks < 8; ++ks) {
    f16x8 pa = *reinterpret_cast<const f16x8*>(
        &P[(qf * 16 + l15) * 256 + (((ks * 4 + kg) ^ (l15 & 7)) * 8)]);
    #pragma unroll
    for (int j = 0; j < 2; ++j) {
      int d = (d0 + j) * 16 + l15;
      f16x8 vb = *reinterpret_cast<const f16x8*>(
          &Vl[d * 256 + (((ks * 4 + kg) ^ (d & 7)) * 8)]);
      oc[j] = __builtin_amdgcn_mfma_f32_16x16x32_f16(pa, vb, oc[j], 0, 0, 0);
    }
  }

  float* houtS = side ? ha : hv;
  #pragma unroll
  for (int j = 0; j < 2; ++j)
    #pragma unroll
    for (int r = 0; r < 4; ++r) {
      int q = qf * 16 + kg * 4 + r;
      int d = (d0 + j) * 16 + l15;
      houtS[(size_t)(b * 64 + q) * 512 + h * 64 + d] =
          oc[j][r] * (1.0f / Ltot[q]);
    }
}

// ---------------------------------------------------------------------------
// K2: out = (hv + ha) @ Wproj.T + bproj. 64x64 MFMA tiles, 16 blocks x 256.
// ---------------------------------------------------------------------------
__device__ __forceinline__ void stage_sum_f16(
    const float* __restrict__ g, const float* __restrict__ g2, int ld,
    int base, int k0, _Float16* __restrict__ lds, int sr, int sq)
{
  const float* p = &g[(size_t)(base + sr) * ld + k0 + sq * 16];
  const float* p2 = g2 ? &g2[(size_t)(base + sr) * ld + k0 + sq * 16] : nullptr;
  float4 v[4];
  #pragma unroll
  for (int i = 0; i < 4; ++i) {
    v[i] = *reinterpret_cast<const float4*>(p + 4 * i);
    if (p2) {
      float4 u = *reinterpret_cast<const float4*>(p2 + 4 * i);
      v[i].x += u.x; v[i].y += u.y; v[i].z += u.z; v[i].w += u.w;
    }
  }
  f16x8 h0 = {(_Float16)v[0].x, (_Float16)v[0].y, (_Float16)v[0].z, (_Float16)v[0].w,
              (_Float16)v[1].x, (_Float16)v[1].y, (_Float16)v[1].z, (_Float16)v[1].w};
  f16x8 h1 = {(_Float16)v[2].x, (_Float16)v[2].y, (_Float16)v[2].z, (_Float16)v[2].w,
              (_Float16)v[3].x, (_Float16)v[3].y, (_Float16)v[3].z, (_Float16)v[3].w};
  int c0 = (sq * 2) ^ (sr & 7);
  int c1 = (sq * 2 + 1) ^ (sr & 7);
  *reinterpret_cast<f16x8*>(&lds[sr * 64 + c0 * 8]) = h0;
  *reinterpret_cast<f16x8*>(&lds[sr * 64 + c1 * 8]) = h1;
}

__global__ __launch_bounds__(256) void proj_out_kernel(
    const float* __restrict__ hv, const float* __restrict__ ha,
    const float* __restrict__ Wproj, const float* __restrict__ bproj,
    float* __restrict__ out)
{
  __shared__ _Float16 As[64 * 64];
  __shared__ _Float16 Ws[64 * 64];
  const int bm = (int)(blockIdx.x >> 3) * 64;
  const int bn = (int)(blockIdx.x & 7) * 64;
  const int tid = threadIdx.x;
  const int lane = tid & 63;
  const int w = tid >> 6;
  const int wm = w >> 1, wn = w & 1;
  const int sr = tid >> 2;
  const int sq = tid & 3;

  f32x4 acc[2][2] = {};
  const int cl = lane & 15;
  const int kg = lane >> 4;

  for (int k0 = 0; k0 < 512; k0 += 64) {
    __syncthreads();
    stage_sum_f16(hv, ha, 512, bm, k0, As, sr, sq);
    stage_sum_f16(Wproj, nullptr, 512, bn, k0, Ws, sr, sq);
    __syncthreads();
    #pragma unroll
    for (int ks = 0; ks < 2; ++ks) {
      f16x8 af[2], bf[2];
      #pragma unroll
      for (int mi = 0; mi < 2; ++mi) {
        int row = wm * 32 + mi * 16 + cl;
        int ch = (ks * 4 + kg) ^ (row & 7);
        af[mi] = *reinterpret_cast<const f16x8*>(&As[row * 64 + ch * 8]);
      }
      #pragma unroll
      for (int ni = 0; ni < 2; ++ni) {
        int col = wn * 32 + ni * 16 + cl;
        int ch = (ks * 4 + kg) ^ (col & 7);
        bf[ni] = *reinterpret_cast<const f16x8*>(&Ws[col * 64 + ch * 8]);
      }
      #pragma unroll
      for (int mi = 0; mi < 2; ++mi)
        #pragma unroll
        for (int ni = 0; ni < 2; ++ni)
          acc[mi][ni] = __builtin_amdgcn_mfma_f32_16x16x32_f16(
              af[mi], bf[ni], acc[mi][ni], 0, 0, 0);
    }
  }

  #pragma unroll
  for (int mi = 0; mi < 2; ++mi)
    #pragma unroll
    for (int ni = 0; ni < 2; ++ni) {
      int row0 = bm + wm * 32 + mi * 16 + kg * 4;
      int col = bn + wn * 32 + ni * 16 + cl;
      float bv = bproj[col];
      #pragma unroll
      for (int r = 0; r < 4; ++r)
        out[(size_t)(row0 + r) * 512 + col] = acc[mi][ni][r] + bv;
    }
}

extern "C" void kernel_launch(void* const* d_in, const int* in_sizes, int n_in,
                              void* d_out, int out_size, void* d_ws, size_t ws_size,
                              hipStream_t stream) {
  const float* xmm   = (const float*)d_in[0];  // [2,64,512]
  const float* xa    = (const float*)d_in[1];  // [2,256,512]
  const float* xv    = (const float*)d_in[2];  // [2,256,512]
  const float* Wq    = (const float*)d_in[3];  // [512,512]
  const float* Wkv   = (const float*)d_in[4];  // [1024,1024]
  const float* Wproj = (const float*)d_in[5];  // [512,512]
  const float* bproj = (const float*)d_in[6];  // [512]
  float* out = (float*)d_out;                  // [2,64,512]
  float* hv = (float*)d_ws;                    // [128][512] f32
  float* ha = hv + 65536;                      // [128][512] f32

  fused_bh_kernel<<<32, 512, 0, stream>>>(xmm, xa, xv, Wq, Wkv, hv, ha);
  proj_out_kernel<<<16, 256, 0, stream>>>(hv, ha, Wproj, bproj, out);
}